// Round 13
// baseline (107.141 us; speedup 1.0000x reference)
//
#include <hip/hip_runtime.h>

// ---------- types ----------
typedef unsigned short u16;
typedef __bf16 bf16x8 __attribute__((ext_vector_type(8)));
typedef float f32x4 __attribute__((ext_vector_type(4)));
typedef float f32x16 __attribute__((ext_vector_type(16)));
typedef u16 u16x4 __attribute__((ext_vector_type(4)));
typedef unsigned int uint;

// B=2, T=2048, DM=1024, H=16, DH=64, M = B*T = 4096
#define DM 1024
#define MROWS 4096
#define TSEQ 2048

static __device__ __forceinline__ u16 f2b(float f) {
  uint u = __builtin_bit_cast(uint, f);
  uint r = (u + 0x7fffu + ((u >> 16) & 1u)) >> 16;  // RTN-even
  return (u16)r;
}

static __device__ __forceinline__ uint pkbf(float a, float b) {
  union { __bf16 h[2]; uint u; } x;
  x.h[0] = (__bf16)a; x.h[1] = (__bf16)b;
  return x.u;
}

// ---------- f32 -> bf16 conversion: x + 4 weights in ONE launch ----------
__global__ __launch_bounds__(256) void cvt_all(
    const float* __restrict__ x, const float* __restrict__ w0,
    const float* __restrict__ w1, const float* __restrict__ w2,
    const float* __restrict__ w3, u16* __restrict__ xo, u16* __restrict__ o0,
    u16* __restrict__ o1, u16* __restrict__ o2, u16* __restrict__ o3,
    float s0) {
  const int bid = blockIdx.x;
  const float* in; u16* out; float scale = 1.0f; int i;
  if (bid < 4096) {
    in = x; out = xo; i = bid * 1024 + threadIdx.x * 4;
  } else {
    int sel = (bid - 4096) >> 10;
    in = (sel == 0) ? w0 : (sel == 1) ? w1 : (sel == 2) ? w2 : w3;
    out = (sel == 0) ? o0 : (sel == 1) ? o1 : (sel == 2) ? o2 : o3;
    if (sel == 0) scale = s0;
    i = ((bid - 4096) & 1023) * 1024 + threadIdx.x * 4;
  }
  float4 v = *(const float4*)(in + i);
  u16x4 o;
  o.x = f2b(v.x * scale); o.y = f2b(v.y * scale);
  o.z = f2b(v.z * scale); o.w = f2b(v.w * scale);
  *(u16x4*)(out + i) = o;
}

// ---------- GEMM core: C[128x128] = A[128xK] * W[128xK]^T, K=1024 ----------
// 2-phase double-buffered (r11-proven; r12's counted-vmcnt was neutral):
// stage(next) issued BEFORE current compute -> drain covered by ds_read+MFMA.
#define SWZ(o) ((o) ^ ((((o) >> 7) & 3) << 4))

static __device__ __forceinline__ void gemm_tile(const u16* __restrict__ A,
                                                 const u16* __restrict__ W,
                                                 int row0, int col0,
                                                 char* lds,
                                                 f32x4 (&acc)[4][4]) {
  const int tid = threadIdx.x;
  const int lane = tid & 63, wid = tid >> 6;
  const int wr = wid >> 1, wc = wid & 1;
  const int lg = lane >> 4, lr = lane & 15;

  const u16* srcA[2]; const u16* srcB[2]; int dst[2];
#pragma unroll
  for (int c = 0; c < 2; ++c) {
    int lin = (c * 256 + tid) * 16;
    int p = SWZ(lin);
    srcA[c] = A + (size_t)(row0 + (p >> 6)) * DM + ((p & 63) >> 1);
    srcB[c] = W + (size_t)(col0 + (p >> 6)) * DM + ((p & 63) >> 1);
    dst[c] = lin;
  }
  int offA[4], offB[4];
#pragma unroll
  for (int m = 0; m < 4; ++m) offA[m] = SWZ((wr * 64 + m * 16 + lr) * 64 + lg * 16);
#pragma unroll
  for (int n = 0; n < 4; ++n) offB[n] = SWZ((wc * 64 + n * 16 + lr) * 64 + lg * 16);

  f32x4 z = {0.f, 0.f, 0.f, 0.f};
#pragma unroll
  for (int m = 0; m < 4; ++m)
#pragma unroll
    for (int n = 0; n < 4; ++n) acc[m][n] = z;

  auto stage = [&](int k0, int buf) {
    char* bA = lds + buf * 16384;
    char* bB = bA + 8192;
#pragma unroll
    for (int c = 0; c < 2; ++c) {
      __builtin_amdgcn_global_load_lds(
          (const __attribute__((address_space(1))) void*)(srcA[c] + k0),
          (__attribute__((address_space(3))) void*)(bA + dst[c]), 16, 0, 0);
      __builtin_amdgcn_global_load_lds(
          (const __attribute__((address_space(1))) void*)(srcB[c] + k0),
          (__attribute__((address_space(3))) void*)(bB + dst[c]), 16, 0, 0);
    }
  };

  stage(0, 0);
  __syncthreads();
  int cur = 0;
  for (int k0 = 0; k0 < DM; k0 += 32) {
    if (k0 + 32 < DM) stage(k0 + 32, cur ^ 1);  // prefetch under compute
    char* bA = lds + cur * 16384;
    char* bB = bA + 8192;
    bf16x8 av[4], bv[4];
#pragma unroll
    for (int m = 0; m < 4; ++m) av[m] = *(const bf16x8*)(bA + offA[m]);
#pragma unroll
    for (int n = 0; n < 4; ++n) bv[n] = *(const bf16x8*)(bB + offB[n]);
    __builtin_amdgcn_s_setprio(1);
#pragma unroll
    for (int m = 0; m < 4; ++m)
#pragma unroll
      for (int n = 0; n < 4; ++n)
        acc[m][n] = __builtin_amdgcn_mfma_f32_16x16x32_bf16(av[m], bv[n], acc[m][n], 0, 0, 0);
    __builtin_amdgcn_s_setprio(0);
    __syncthreads();
    cur ^= 1;
  }
}

// ---------- fused QKV projection ----------
// Q/K: MFMA-fragment order Q'[bh][tw][c][hi][ln][j]; staged via row-col LDS
// tile then linear b128 stores. V: output-linear transposed LDS layout.
__global__ __launch_bounds__(256) void qkv_gemm(
    const u16* __restrict__ xb, const u16* __restrict__ Wqb,
    const u16* __restrict__ Wkb, const u16* __restrict__ Wvb,
    const float* __restrict__ bq, const float* __restrict__ bk,
    const float* __restrict__ bv, u16* __restrict__ Qx, u16* __restrict__ Kx,
    u16* __restrict__ Vx) {
  __shared__ char lds[32768];
  const int seg = blockIdx.x >> 3, nt = blockIdx.x & 7;
  const int row0 = blockIdx.y * 128, col0 = nt * 128;
  const u16* W = (seg == 0) ? Wqb : (seg == 1) ? Wkb : Wvb;
  const float* bias = (seg == 0) ? bq : (seg == 1) ? bk : bv;
  // Q carries 1/sqrt(64) * log2(e) so attention works in exp2 domain
  const float bscale = (seg == 0) ? 0.18033688011112042f : 1.0f;

  f32x4 acc[4][4];
  gemm_tile(xb, W, row0, col0, lds, acc);

  const int tid = threadIdx.x;
  const int lane = tid & 63, wid = tid >> 6;
  const int wr = wid >> 1, wc = wid & 1;
  const int lg = lane >> 4, lr = lane & 15;

  float bcol[4];
#pragma unroll
  for (int n = 0; n < 4; ++n) bcol[n] = bias[col0 + wc * 64 + n * 16 + lr] * bscale;

  if (seg < 2) {
    // row-col LDS tile, 16B-granule row swizzle
#pragma unroll
    for (int m = 0; m < 4; ++m)
#pragma unroll
      for (int n = 0; n < 4; ++n) {
        int colB = (wc * 64 + n * 16 + lr) * 2;
#pragma unroll
        for (int r = 0; r < 4; ++r) {
          int row = wr * 64 + m * 16 + lg * 4 + r;
          *(u16*)(lds + row * 256 + (colB ^ ((row & 7) << 4))) =
              f2b(acc[m][n][r] + bcol[n]);
        }
      }
  } else {
    // V: output-linear transposed layout.
    const int hi2 = lg & 1, jh = lg >> 1;
#pragma unroll
    for (int m = 0; m < 4; ++m) {
      const int c = m & 1;
      const int ktl = wr * 2 + (m >> 1);
#pragma unroll
      for (int n = 0; n < 4; ++n) {
        int col = wc * 64 + n * 16 + lr;
        int hloc = col >> 6, dcol = col & 63;
        int hh = dcol >> 5, dp = dcol & 31;
        int byte = (hloc * 4 + ktl) * 4096 + (((c * 2 + hh) * 2 + hi2) * 512) +
                   dp * 16 + jh * 8;
        byte ^= ((dp & 3) << 5) ^ (hi2 << 6);
        u16x4 pk;
        pk.x = f2b(acc[m][n][0] + bcol[n]);
        pk.y = f2b(acc[m][n][1] + bcol[n]);
        pk.z = f2b(acc[m][n][2] + bcol[n]);
        pk.w = f2b(acc[m][n][3] + bcol[n]);
        *(u16x4*)(lds + byte) = pk;
      }
    }
  }
  __syncthreads();

  const int st = tid >> 5, lnq = tid & 31;
  const int bI = row0 >> 11;
  if (seg < 2) {
    u16* out = (seg == 0) ? Qx : Kx;
    const int hloc = st & 1, twloc = st >> 1;
    const int h = (col0 >> 6) + hloc;
    const int tw = ((row0 & 2047) >> 5) + twloc;
    u16* base = out + ((size_t)(bI * 16 + h) * 64 + tw) * 2048;
#pragma unroll
    for (int ch = 0; ch < 8; ++ch) {
      int q = ch * 256 + lnq * 8;
      int c = q >> 9, hi2 = (q >> 8) & 1;
      int row = twloc * 32 + lnq;
      int colB = hloc * 128 + c * 32 + hi2 * 16;
      bf16x8 v = *(const bf16x8*)(lds + row * 256 + (colB ^ ((row & 7) << 4)));
      *(bf16x8*)(base + q) = v;
    }
  } else {
    const int hloc = st & 1, ktl = st >> 1;
    const int h = (col0 >> 6) + hloc;
    const int kt = ((row0 & 2047) >> 5) + ktl;
    u16* base = Vx + ((size_t)(bI * 16 + h) * 64 + kt) * 2048;
#pragma unroll
    for (int ch = 0; ch < 8; ++ch) {
      int hi2 = ch & 1;
      int byte = (hloc * 4 + ktl) * 4096 + ch * 512 + lnq * 16;
      byte ^= ((lnq & 3) << 5) ^ (hi2 << 6);
      bf16x8 v = *(const bf16x8*)(lds + byte);
      *(bf16x8*)(base + ch * 256 + lnq * 8) = v;
    }
  }
}

// ---------- flash attention (causal), balanced-pair blocks ---------------
// 2048 work items = 32-row q-tiles (qt32 in 0..63) x 32 bh. Block = 4 waves
// processes the constant-sum pair (63-p, p) SEQUENTIALLY; each item is
// 4-way kv-split across the 4 waves -> per-block work ~= 17 units, uniform
// across all 1024 blocks (kills the 2x makespan imbalance of per-qt blocks).
// Loop body identical to r11 (register-resident, no inner barriers).
// Merge = r8-verified pairwise tree via 2x8KB LDS buffers.
__global__ __launch_bounds__(256, 4) void attn_kernel(const u16* __restrict__ Qx,
                                                      const u16* __restrict__ Kx,
                                                      const u16* __restrict__ Vx,
                                                      u16* __restrict__ Aout) {
  __shared__ float bufA[64][32];   // 8 KB partial-O
  __shared__ float bufB[64][32];   // 8 KB
  __shared__ float mmlA[64][2], mmlB[64][2];
  const int tid = threadIdx.x, lane = tid & 63, spl = tid >> 6;
  const int hi = lane >> 5, ln = lane & 31;
  const int id = blockIdx.x + (blockIdx.y << 5);
  const int xcd = id & 7, idx = id >> 3;
  const int bh = xcd * 4 + (idx & 3);   // 4 heads per XCD (L2-resident K/V)
  const int p = idx >> 2;               // pair index 0..31
  const int b = bh >> 4, h = bh & 15;
  const int sw8 = lane & 7;

  const u16* Kt = Kx + (size_t)bh * 64 * 2048;
  const u16* Vt = Vx + (size_t)bh * 64 * 2048;

  for (int it = 0; it < 2; ++it) {
    const int qt32 = it ? p : 63 - p;   // big item first
    const int q0 = qt32 * 32;
    const int ntile = qt32 + 1;
    const int tbeg = (spl * ntile) >> 2;
    const int tend = ((spl + 1) * ntile) >> 2;

    const u16* Qp = Qx + ((size_t)bh * 64 + qt32) * 2048;
    bf16x8 qf[4];
#pragma unroll
    for (int c = 0; c < 4; ++c)
      qf[c] = *(const bf16x8*)(Qp + c * 512 + hi * 256 + ln * 8);

    f32x16 Oa, Ob;
#pragma unroll
    for (int r = 0; r < 16; ++r) { Oa[r] = 0.f; Ob[r] = 0.f; }
    float m = -1e30f, l = 0.f;  // m row-consistent; l PER-LANE partial

    bf16x8 kf[4], vf[4];
    auto loadK = [&](int kt) {
      const u16* Kp = Kt + (size_t)kt * 2048;
#pragma unroll
      for (int c = 0; c < 4; ++c)
        kf[c] = *(const bf16x8*)(Kp + c * 512 + hi * 256 + ln * 8);
    };
    auto loadV = [&](int kt) {
      const u16* Vp = Vt + (size_t)kt * 2048;
#pragma unroll
      for (int c = 0; c < 4; ++c)
        vf[c] = *(const bf16x8*)(Vp + c * 512 + hi * 256 + ln * 8);
    };

    if (tbeg < tend) loadK(tbeg);
    for (int kt = tbeg; kt < tend; ++kt) {
      loadV(kt);  // issued now, consumed after softmax -> latency hidden
      f32x16 S;
#pragma unroll
      for (int r = 0; r < 16; ++r) S[r] = 0.f;
      __builtin_amdgcn_s_setprio(1);
#pragma unroll
      for (int c = 0; c < 4; ++c)
        S = __builtin_amdgcn_mfma_f32_32x32x16_bf16(kf[c], qf[c], S, 0, 0, 0);
      __builtin_amdgcn_s_setprio(0);
      if (kt + 1 < tend) loadK(kt + 1);  // next K in flight under softmax+PV
      if (kt == ntile - 1) {  // diagonal tile
        const int q = q0 + ln;
#pragma unroll
        for (int r = 0; r < 16; ++r) {
          int kv = kt * 32 + (r & 3) + 8 * (r >> 2) + 4 * hi;
          if (kv > q) S[r] = -1e38f;
        }
      }
      // per-lane max tree; no cross-lane shfl in common path
      float a0 = fmaxf(fmaxf(S[0], S[1]), S[2]);
      float a1 = fmaxf(fmaxf(S[3], S[4]), S[5]);
      float a2 = fmaxf(fmaxf(S[6], S[7]), S[8]);
      float a3 = fmaxf(fmaxf(S[9], S[10]), S[11]);
      float a4 = fmaxf(fmaxf(S[12], S[13]), S[14]);
      float mx = fmaxf(fmaxf(fmaxf(a0, a1), fmaxf(a2, a3)), fmaxf(a4, S[15]));
      if (!__all(mx - m <= 8.f)) {  // defer-max (T13)
        float nm = fmaxf(m, mx);
        nm = fmaxf(nm, __shfl_xor(nm, 32));  // row-wide merge only here
        float sf = __builtin_amdgcn_exp2f(m - nm);
        m = nm; l *= sf;
#pragma unroll
        for (int r = 0; r < 16; ++r) { Oa[r] *= sf; Ob[r] *= sf; }
      }
#pragma unroll
      for (int r = 0; r < 16; ++r) S[r] = __builtin_amdgcn_exp2f(S[r] - m);
      float ts = ((S[0] + S[1]) + (S[2] + S[3])) + ((S[4] + S[5]) + (S[6] + S[7]));
      ts += ((S[8] + S[9]) + (S[10] + S[11])) + ((S[12] + S[13]) + (S[14] + S[15]));
      l += ts;  // per-lane; merged at end
      uint pw[8];
#pragma unroll
      for (int i = 0; i < 8; ++i) pw[i] = pkbf(S[2 * i], S[2 * i + 1]);
      __builtin_amdgcn_s_setprio(1);
#pragma unroll
      for (int c = 0; c < 2; ++c) {
        union { uint w[4]; bf16x8 v; } pf;
        pf.w[0] = pw[4 * c + 0]; pf.w[1] = pw[4 * c + 1];
        pf.w[2] = pw[4 * c + 2]; pf.w[3] = pw[4 * c + 3];
        Oa = __builtin_amdgcn_mfma_f32_32x32x16_bf16(vf[2 * c + 0], pf.v, Oa, 0, 0, 0);
        Ob = __builtin_amdgcn_mfma_f32_32x32x16_bf16(vf[2 * c + 1], pf.v, Ob, 0, 0, 0);
      }
      __builtin_amdgcn_s_setprio(0);
    }

    // ---- 4-way kv-split merge: pairwise tree (0<-1), (2<-3), (0<-2) ----
    union uo { f32x16 v; f32x4 q[4]; };
    auto writePart = [&](float* buf, float* mml) {
      uo ua, ub; ua.v = Oa; ub.v = Ob;
      char* bc = (char*)buf;
#pragma unroll
      for (int c = 0; c < 4; ++c) {
        *(f32x4*)(bc + lane * 128 + ((c ^ sw8) * 16)) = ua.q[c];
        *(f32x4*)(bc + lane * 128 + (((c + 4) ^ sw8) * 16)) = ub.q[c];
      }
      mml[lane * 2 + 0] = m;
      mml[lane * 2 + 1] = l;
    };
    auto mergePart = [&](const float* buf, const float* mml) {
      float mY = mml[lane * 2 + 0], lY = mml[lane * 2 + 1];
      const char* bc = (const char*)buf;
      f32x4 rb[8];
#pragma unroll
      for (int c = 0; c < 8; ++c)
        rb[c] = *(const f32x4*)(bc + lane * 128 + ((c ^ sw8) * 16));
      float M = fmaxf(m, mY);
      float eX = __builtin_amdgcn_exp2f(m - M);
      float eY = __builtin_amdgcn_exp2f(mY - M);
      uo ua, ub; ua.v = Oa; ub.v = Ob;
#pragma unroll
      for (int c = 0; c < 4; ++c) {
        ua.q[c] = ua.q[c] * eX + rb[c] * eY;
        ub.q[c] = ub.q[c] * eX + rb[c + 4] * eY;
      }
      Oa = ua.v; Ob = ub.v;
      l = l * eX + lY * eY;
      m = M;
    };

    if (spl == 1) writePart(&bufA[0][0], &mmlA[0][0]);
    if (spl == 3) writePart(&bufB[0][0], &mmlB[0][0]);
    __syncthreads();
    if (spl == 0) mergePart(&bufA[0][0], &mmlA[0][0]);
    if (spl == 2) mergePart(&bufB[0][0], &mmlB[0][0]);
    __syncthreads();
    if (spl == 2) writePart(&bufA[0][0], &mmlA[0][0]);
    __syncthreads();
    if (spl == 0) {
      mergePart(&bufA[0][0], &mmlA[0][0]);
      float lr = l + __shfl_xor(l, 32);
      const float inv = 1.f / lr;
      // epilogue: transpose O^T via LDS (reuse bufA), coalesced store
      __threadfence_block();
      char* Tc = (char*)&bufA[0][0];
#pragma unroll
      for (int i = 0; i < 8; ++i) {
        int d0 = (2 * i & 3) + 8 * ((2 * i) >> 2) + 4 * hi;
        uint wA = pkbf(Oa[2 * i] * inv, Oa[2 * i + 1] * inv);
        *(uint*)(Tc + (ln * 128 + ((d0 * 2) ^ ((ln & 7) << 4)))) = wA;
        uint wB = pkbf(Ob[2 * i] * inv, Ob[2 * i + 1] * inv);
        *(uint*)(Tc + (ln * 128 + (((d0 + 32) * 2) ^ ((ln & 7) << 4)))) = wB;
      }
      __threadfence_block();
      u16* Ap = Aout + (size_t)b * TSEQ * DM + h * 64 + (size_t)(q0 + ln) * DM;
#pragma unroll
      for (int j = 0; j < 4; ++j) {
        int oct = hi * 4 + j;
        bf16x8 v = *(const bf16x8*)(Tc + (ln * 128 + ((oct * 16) ^ ((ln & 7) << 4))));
        *(bf16x8*)(Ap + oct * 8) = v;
      }
    }
    __syncthreads();  // bufA free before next item
  }
}

// ---------- output projection: out = attn @ Wo^T + bo (f32 out) ----------
__global__ __launch_bounds__(256) void out_gemm(const u16* __restrict__ attn,
                                                const u16* __restrict__ Wob,
                                                const float* __restrict__ bo,
                                                float* __restrict__ out) {
  __shared__ char lds[32768];
  const int row0 = blockIdx.y * 128, col0 = blockIdx.x * 128;
  f32x4 acc[4][4];
  gemm_tile(attn, Wob, row0, col0, lds, acc);

  const int tid = threadIdx.x;
  const int lane = tid & 63, wid = tid >> 6;
  const int wr = wid >> 1, wc = wid & 1;
  const int lg = lane >> 4, lr = lane & 15;
#pragma unroll
  for (int m = 0; m < 4; ++m)
#pragma unroll
    for (int n = 0; n < 4; ++n) {
      int col = col0 + wc * 64 + n * 16 + lr;
      float b = bo[col];
#pragma unroll
      for (int r = 0; r < 4; ++r) {
        int row = row0 + wr * 64 + m * 16 + lg * 4 + r;
        out[(size_t)row * DM + col] = acc[m][n][r] + b;
      }
    }
}

extern "C" void kernel_launch(void* const* d_in, const int* in_sizes, int n_in,
                              void* d_out, int out_size, void* d_ws, size_t ws_size,
                              hipStream_t stream) {
  const float* x = (const float*)d_in[0];
  const float* Wq = (const float*)d_in[1];
  const float* bq = (const float*)d_in[2];
  const float* Wk = (const float*)d_in[3];
  const float* bk = (const float*)d_in[4];
  const float* Wv = (const float*)d_in[5];
  const float* bv = (const float*)d_in[6];
  const float* Wo = (const float*)d_in[7];
  const float* bo = (const float*)d_in[8];

  char* ws = (char*)d_ws;
  const size_t MB = 1024 * 1024;
  u16* xb = (u16*)(ws);             // 8 MB (x bf16; reused as attn out later)
  u16* Wqb = (u16*)(ws + 8 * MB);   // 2 MB
  u16* Wkb = (u16*)(ws + 10 * MB);  // 2 MB
  u16* Wvb = (u16*)(ws + 12 * MB);  // 2 MB
  u16* Wob = (u16*)(ws + 14 * MB);  // 2 MB
  u16* Qf = (u16*)(ws + 16 * MB);   // 8 MB (fragment-order Q')
  u16* Kf = (u16*)(ws + 24 * MB);   // 8 MB (fragment-order K')
  u16* Vf = (u16*)(ws + 32 * MB);   // 8 MB (fragment-order V')  total 40 MB
  u16* attnb = xb;                  // alias: xb dead after qkv_gemm

  // Wq carries 1/sqrt(Dh) * log2(e); one launch for all conversions
  cvt_all<<<8192, 256, 0, stream>>>(x, Wq, Wk, Wv, Wo, xb, Wqb, Wkb, Wvb, Wob,
                                    0.18033688011112042f);

  qkv_gemm<<<dim3(24, 32), 256, 0, stream>>>(xb, Wqb, Wkb, Wvb, bq, bk, bv, Qf, Kf, Vf);
  attn_kernel<<<dim3(32, 32), 256, 0, stream>>>(Qf, Kf, Vf, attnb);
  out_gemm<<<dim3(8, 32), 256, 0, stream>>>(attnb, Wob, bo, (float*)d_out);
}

// Round 14
// 92.125 us; speedup vs baseline: 1.1630x; 1.1630x over previous
//
#include <hip/hip_runtime.h>

// ---------- types ----------
typedef unsigned short u16;
typedef __bf16 bf16x8 __attribute__((ext_vector_type(8)));
typedef float f32x4 __attribute__((ext_vector_type(4)));
typedef float f32x16 __attribute__((ext_vector_type(16)));
typedef u16 u16x4 __attribute__((ext_vector_type(4)));
typedef unsigned int uint;

// B=2, T=2048, DM=1024, H=16, DH=64, M = B*T = 4096
#define DM 1024
#define MROWS 4096
#define TSEQ 2048

static __device__ __forceinline__ u16 f2b(float f) {
  uint u = __builtin_bit_cast(uint, f);
  uint r = (u + 0x7fffu + ((u >> 16) & 1u)) >> 16;  // RTN-even
  return (u16)r;
}

static __device__ __forceinline__ uint pkbf(float a, float b) {
  union { __bf16 h[2]; uint u; } x;
  x.h[0] = (__bf16)a; x.h[1] = (__bf16)b;
  return x.u;
}

// ---------- f32 -> bf16 conversion: x + 4 weights in ONE launch ----------
__global__ __launch_bounds__(256) void cvt_all(
    const float* __restrict__ x, const float* __restrict__ w0,
    const float* __restrict__ w1, const float* __restrict__ w2,
    const float* __restrict__ w3, u16* __restrict__ xo, u16* __restrict__ o0,
    u16* __restrict__ o1, u16* __restrict__ o2, u16* __restrict__ o3,
    float s0) {
  const int bid = blockIdx.x;
  const float* in; u16* out; float scale = 1.0f; int i;
  if (bid < 4096) {
    in = x; out = xo; i = bid * 1024 + threadIdx.x * 4;
  } else {
    int sel = (bid - 4096) >> 10;
    in = (sel == 0) ? w0 : (sel == 1) ? w1 : (sel == 2) ? w2 : w3;
    out = (sel == 0) ? o0 : (sel == 1) ? o1 : (sel == 2) ? o2 : o3;
    if (sel == 0) scale = s0;
    i = ((bid - 4096) & 1023) * 1024 + threadIdx.x * 4;
  }
  float4 v = *(const float4*)(in + i);
  u16x4 o;
  o.x = f2b(v.x * scale); o.y = f2b(v.y * scale);
  o.z = f2b(v.z * scale); o.w = f2b(v.w * scale);
  *(u16x4*)(out + i) = o;
}

// ---------- GEMM core: C[128x128] = A[128xK] * W[128xK]^T, K=1024 ----------
// 2-phase double-buffered (proven ceiling for this structure ~650 TF):
// stage(next) issued BEFORE current compute -> drain covered by ds_read+MFMA.
#define SWZ(o) ((o) ^ ((((o) >> 7) & 3) << 4))

static __device__ __forceinline__ void gemm_tile(const u16* __restrict__ A,
                                                 const u16* __restrict__ W,
                                                 int row0, int col0,
                                                 char* lds,
                                                 f32x4 (&acc)[4][4]) {
  const int tid = threadIdx.x;
  const int lane = tid & 63, wid = tid >> 6;
  const int wr = wid >> 1, wc = wid & 1;
  const int lg = lane >> 4, lr = lane & 15;

  const u16* srcA[2]; const u16* srcB[2]; int dst[2];
#pragma unroll
  for (int c = 0; c < 2; ++c) {
    int lin = (c * 256 + tid) * 16;
    int p = SWZ(lin);
    srcA[c] = A + (size_t)(row0 + (p >> 6)) * DM + ((p & 63) >> 1);
    srcB[c] = W + (size_t)(col0 + (p >> 6)) * DM + ((p & 63) >> 1);
    dst[c] = lin;
  }
  int offA[4], offB[4];
#pragma unroll
  for (int m = 0; m < 4; ++m) offA[m] = SWZ((wr * 64 + m * 16 + lr) * 64 + lg * 16);
#pragma unroll
  for (int n = 0; n < 4; ++n) offB[n] = SWZ((wc * 64 + n * 16 + lr) * 64 + lg * 16);

  f32x4 z = {0.f, 0.f, 0.f, 0.f};
#pragma unroll
  for (int m = 0; m < 4; ++m)
#pragma unroll
    for (int n = 0; n < 4; ++n) acc[m][n] = z;

  auto stage = [&](int k0, int buf) {
    char* bA = lds + buf * 16384;
    char* bB = bA + 8192;
#pragma unroll
    for (int c = 0; c < 2; ++c) {
      __builtin_amdgcn_global_load_lds(
          (const __attribute__((address_space(1))) void*)(srcA[c] + k0),
          (__attribute__((address_space(3))) void*)(bA + dst[c]), 16, 0, 0);
      __builtin_amdgcn_global_load_lds(
          (const __attribute__((address_space(1))) void*)(srcB[c] + k0),
          (__attribute__((address_space(3))) void*)(bB + dst[c]), 16, 0, 0);
    }
  };

  stage(0, 0);
  __syncthreads();
  int cur = 0;
  for (int k0 = 0; k0 < DM; k0 += 32) {
    if (k0 + 32 < DM) stage(k0 + 32, cur ^ 1);  // prefetch under compute
    char* bA = lds + cur * 16384;
    char* bB = bA + 8192;
    bf16x8 av[4], bv[4];
#pragma unroll
    for (int m = 0; m < 4; ++m) av[m] = *(const bf16x8*)(bA + offA[m]);
#pragma unroll
    for (int n = 0; n < 4; ++n) bv[n] = *(const bf16x8*)(bB + offB[n]);
    __builtin_amdgcn_s_setprio(1);
#pragma unroll
    for (int m = 0; m < 4; ++m)
#pragma unroll
      for (int n = 0; n < 4; ++n)
        acc[m][n] = __builtin_amdgcn_mfma_f32_16x16x32_bf16(av[m], bv[n], acc[m][n], 0, 0, 0);
    __builtin_amdgcn_s_setprio(0);
    __syncthreads();
    cur ^= 1;
  }
}

// ---------- fused QKV projection ----------
// Q/K: MFMA-fragment order Q'[bh][tw][c][hi][ln][j]; staged via row-col LDS
// tile then linear b128 stores. V: output-linear transposed LDS layout --
// each thread's 4 acc values = one u16x4 write; store phase = pure linear
// b128 reads.
__global__ __launch_bounds__(256) void qkv_gemm(
    const u16* __restrict__ xb, const u16* __restrict__ Wqb,
    const u16* __restrict__ Wkb, const u16* __restrict__ Wvb,
    const float* __restrict__ bq, const float* __restrict__ bk,
    const float* __restrict__ bv, u16* __restrict__ Qx, u16* __restrict__ Kx,
    u16* __restrict__ Vx) {
  __shared__ char lds[32768];
  const int seg = blockIdx.x >> 3, nt = blockIdx.x & 7;
  const int row0 = blockIdx.y * 128, col0 = nt * 128;
  const u16* W = (seg == 0) ? Wqb : (seg == 1) ? Wkb : Wvb;
  const float* bias = (seg == 0) ? bq : (seg == 1) ? bk : bv;
  // Q carries 1/sqrt(64) * log2(e) so attention works in exp2 domain
  const float bscale = (seg == 0) ? 0.18033688011112042f : 1.0f;

  f32x4 acc[4][4];
  gemm_tile(xb, W, row0, col0, lds, acc);

  const int tid = threadIdx.x;
  const int lane = tid & 63, wid = tid >> 6;
  const int wr = wid >> 1, wc = wid & 1;
  const int lg = lane >> 4, lr = lane & 15;

  float bcol[4];
#pragma unroll
  for (int n = 0; n < 4; ++n) bcol[n] = bias[col0 + wc * 64 + n * 16 + lr] * bscale;

  if (seg < 2) {
    // row-col LDS tile, 16B-granule row swizzle
#pragma unroll
    for (int m = 0; m < 4; ++m)
#pragma unroll
      for (int n = 0; n < 4; ++n) {
        int colB = (wc * 64 + n * 16 + lr) * 2;
#pragma unroll
        for (int r = 0; r < 4; ++r) {
          int row = wr * 64 + m * 16 + lg * 4 + r;
          *(u16*)(lds + row * 256 + (colB ^ ((row & 7) << 4))) =
              f2b(acc[m][n][r] + bcol[n]);
        }
      }
  } else {
    // V: output-linear transposed layout.
    const int hi2 = lg & 1, jh = lg >> 1;
#pragma unroll
    for (int m = 0; m < 4; ++m) {
      const int c = m & 1;
      const int ktl = wr * 2 + (m >> 1);
#pragma unroll
      for (int n = 0; n < 4; ++n) {
        int col = wc * 64 + n * 16 + lr;
        int hloc = col >> 6, dcol = col & 63;
        int hh = dcol >> 5, dp = dcol & 31;
        int byte = (hloc * 4 + ktl) * 4096 + (((c * 2 + hh) * 2 + hi2) * 512) +
                   dp * 16 + jh * 8;
        byte ^= ((dp & 3) << 5) ^ (hi2 << 6);
        u16x4 pk;
        pk.x = f2b(acc[m][n][0] + bcol[n]);
        pk.y = f2b(acc[m][n][1] + bcol[n]);
        pk.z = f2b(acc[m][n][2] + bcol[n]);
        pk.w = f2b(acc[m][n][3] + bcol[n]);
        *(u16x4*)(lds + byte) = pk;
      }
    }
  }
  __syncthreads();

  const int st = tid >> 5, lnq = tid & 31;
  const int bI = row0 >> 11;
  if (seg < 2) {
    u16* out = (seg == 0) ? Qx : Kx;
    const int hloc = st & 1, twloc = st >> 1;
    const int h = (col0 >> 6) + hloc;
    const int tw = ((row0 & 2047) >> 5) + twloc;
    u16* base = out + ((size_t)(bI * 16 + h) * 64 + tw) * 2048;
#pragma unroll
    for (int ch = 0; ch < 8; ++ch) {
      int q = ch * 256 + lnq * 8;
      int c = q >> 9, hi2 = (q >> 8) & 1;
      int row = twloc * 32 + lnq;
      int colB = hloc * 128 + c * 32 + hi2 * 16;
      bf16x8 v = *(const bf16x8*)(lds + row * 256 + (colB ^ ((row & 7) << 4)));
      *(bf16x8*)(base + q) = v;
    }
  } else {
    const int hloc = st & 1, ktl = st >> 1;
    const int h = (col0 >> 6) + hloc;
    const int kt = ((row0 & 2047) >> 5) + ktl;
    u16* base = Vx + ((size_t)(bI * 16 + h) * 64 + kt) * 2048;
#pragma unroll
    for (int ch = 0; ch < 8; ++ch) {
      int hi2 = ch & 1;
      int byte = (hloc * 4 + ktl) * 4096 + ch * 512 + lnq * 16;
      byte ^= ((lnq & 3) << 5) ^ (hi2 << 6);
      bf16x8 v = *(const bf16x8*)(lds + byte);
      *(bf16x8*)(base + ch * 256 + lnq * 8) = v;
    }
  }
}

// ---------- flash attention (causal) ------------------------------------
// r7/r11 structure: register-resident, NO inner barriers. Block = one
// 64-row q-tile, 4 waves = {2 row-halves} x {2 kv-splits} (row-halves SHARE
// kv tiles -> L2-friendly; r13 lesson: disjoint 4-way split tripled FETCH).
// Fragment-order 1KB wave loads; kv-split merge via LDS at end. Single K
// buffer (r8/r10: live set ~115 regs; any extra buffer spills at 128 cap).
// Per-lane l & defer-check: no cross-lane shfl in the common path.
__global__ __launch_bounds__(256, 4) void attn_kernel(const u16* __restrict__ Qx,
                                                      const u16* __restrict__ Kx,
                                                      const u16* __restrict__ Vx,
                                                      u16* __restrict__ Aout) {
  __shared__ float mrg[2][64][32];  // per row-half merge buf (16 KB)
  __shared__ float mml[2][64][2];   // per-lane (m,l)
  const int tid = threadIdx.x, lane = tid & 63, wid = tid >> 6;
  const int hi = lane >> 5, ln = lane & 31;
  const int half = wid & 1, spl = wid >> 1;
  const int id = blockIdx.x + (blockIdx.y << 5);
  const int xcd = id & 7, idx = id >> 3;
  const int bh = xcd * 4 + (idx & 3);   // 4 heads per XCD (L2-resident K/V)
  const int qt = 31 - (idx >> 2);       // LPT: big q-tiles first
  const int b = bh >> 4, h = bh & 15;
  const int q0 = qt * 64 + half * 32;
  const int ntile = (q0 >> 5) + 1;
  const int halfn = (ntile + 1) >> 1;
  const int tbeg = spl ? halfn : 0;
  const int tend = spl ? ntile : halfn;

  const u16* Qp = Qx + ((size_t)bh * 64 + (q0 >> 5)) * 2048;
  const u16* Kt = Kx + (size_t)bh * 64 * 2048;
  const u16* Vt = Vx + (size_t)bh * 64 * 2048;

  bf16x8 qf[4];
#pragma unroll
  for (int c = 0; c < 4; ++c)
    qf[c] = *(const bf16x8*)(Qp + c * 512 + hi * 256 + ln * 8);

  f32x16 Oa, Ob;
#pragma unroll
  for (int r = 0; r < 16; ++r) { Oa[r] = 0.f; Ob[r] = 0.f; }
  float m = -1e30f, l = 0.f;  // m row-consistent; l PER-LANE partial

  bf16x8 kf[4], vf[4];
  auto loadK = [&](int kt) {
    const u16* Kp = Kt + (size_t)kt * 2048;
#pragma unroll
    for (int c = 0; c < 4; ++c)
      kf[c] = *(const bf16x8*)(Kp + c * 512 + hi * 256 + ln * 8);
  };
  auto loadV = [&](int kt) {
    const u16* Vp = Vt + (size_t)kt * 2048;
#pragma unroll
    for (int c = 0; c < 4; ++c)
      vf[c] = *(const bf16x8*)(Vp + c * 512 + hi * 256 + ln * 8);
  };

  if (tbeg < tend) loadK(tbeg);
  for (int kt = tbeg; kt < tend; ++kt) {
    loadV(kt);  // issued now, consumed after softmax -> latency hidden
    f32x16 S;
#pragma unroll
    for (int r = 0; r < 16; ++r) S[r] = 0.f;
    __builtin_amdgcn_s_setprio(1);
#pragma unroll
    for (int c = 0; c < 4; ++c)
      S = __builtin_amdgcn_mfma_f32_32x32x16_bf16(kf[c], qf[c], S, 0, 0, 0);
    __builtin_amdgcn_s_setprio(0);
    if (kt + 1 < tend) loadK(kt + 1);  // next K in flight under softmax+PV
    if (kt == ntile - 1) {  // diagonal tile
      const int q = q0 + ln;
#pragma unroll
      for (int r = 0; r < 16; ++r) {
        int kv = kt * 32 + (r & 3) + 8 * (r >> 2) + 4 * hi;
        if (kv > q) S[r] = -1e38f;
      }
    }
    // per-lane max tree; no cross-lane shfl in common path
    float a0 = fmaxf(fmaxf(S[0], S[1]), S[2]);
    float a1 = fmaxf(fmaxf(S[3], S[4]), S[5]);
    float a2 = fmaxf(fmaxf(S[6], S[7]), S[8]);
    float a3 = fmaxf(fmaxf(S[9], S[10]), S[11]);
    float a4 = fmaxf(fmaxf(S[12], S[13]), S[14]);
    float mx = fmaxf(fmaxf(fmaxf(a0, a1), fmaxf(a2, a3)), fmaxf(a4, S[15]));
    if (!__all(mx - m <= 8.f)) {  // defer-max (T13); m stays row-consistent
      float nm = fmaxf(m, mx);
      nm = fmaxf(nm, __shfl_xor(nm, 32));  // row-wide merge only here
      float sf = __builtin_amdgcn_exp2f(m - nm);
      m = nm; l *= sf;
#pragma unroll
      for (int r = 0; r < 16; ++r) { Oa[r] *= sf; Ob[r] *= sf; }
    }
#pragma unroll
    for (int r = 0; r < 16; ++r) S[r] = __builtin_amdgcn_exp2f(S[r] - m);
    float ts = ((S[0] + S[1]) + (S[2] + S[3])) + ((S[4] + S[5]) + (S[6] + S[7]));
    ts += ((S[8] + S[9]) + (S[10] + S[11])) + ((S[12] + S[13]) + (S[14] + S[15]));
    l += ts;  // per-lane; merged at end
    uint pw[8];
#pragma unroll
    for (int i = 0; i < 8; ++i) pw[i] = pkbf(S[2 * i], S[2 * i + 1]);
    __builtin_amdgcn_s_setprio(1);
#pragma unroll
    for (int c = 0; c < 2; ++c) {
      union { uint w[4]; bf16x8 v; } pf;
      pf.w[0] = pw[4 * c + 0]; pf.w[1] = pw[4 * c + 1];
      pf.w[2] = pw[4 * c + 2]; pf.w[3] = pw[4 * c + 3];
      Oa = __builtin_amdgcn_mfma_f32_32x32x16_bf16(vf[2 * c + 0], pf.v, Oa, 0, 0, 0);
      Ob = __builtin_amdgcn_mfma_f32_32x32x16_bf16(vf[2 * c + 1], pf.v, Ob, 0, 0, 0);
    }
    __builtin_amdgcn_s_setprio(0);
  }

  // ---- kv-split merge: spl1 writes (O,m,l) to LDS, spl0 merges ----
  union uo { f32x16 v; f32x4 q[4]; };
  const int sw8 = lane & 7;
  char* moc = (char*)&mrg[half][0][0];
  if (spl == 1) {
    uo ua, ub; ua.v = Oa; ub.v = Ob;
#pragma unroll
    for (int c = 0; c < 4; ++c) {
      *(f32x4*)(moc + lane * 128 + ((c ^ sw8) * 16)) = ua.q[c];
      *(f32x4*)(moc + lane * 128 + (((c + 4) ^ sw8) * 16)) = ub.q[c];
    }
    mml[half][lane][0] = m;
    mml[half][lane][1] = l;
  }
  __syncthreads();
  if (spl == 1) return;

  {
    float mY = mml[half][lane][0], lY = mml[half][lane][1];
    f32x4 rb[8];
#pragma unroll
    for (int c = 0; c < 8; ++c)
      rb[c] = *(const f32x4*)(moc + lane * 128 + ((c ^ sw8) * 16));
    float M = fmaxf(m, mY);
    float eX = __builtin_amdgcn_exp2f(m - M);
    float eY = __builtin_amdgcn_exp2f(mY - M);
    uo ua, ub; ua.v = Oa; ub.v = Ob;
#pragma unroll
    for (int c = 0; c < 4; ++c) {
      ua.q[c] = ua.q[c] * eX + rb[c] * eY;
      ub.q[c] = ub.q[c] * eX + rb[c + 4] * eY;
    }
    Oa = ua.v; Ob = ub.v;
    l = l * eX + lY * eY;
  }

  float lr = l + __shfl_xor(l, 32);
  const float inv = 1.f / lr;

  // epilogue: transpose O^T via LDS (reuse moc), coalesced store
  __threadfence_block();
  char* Tc = moc;
#pragma unroll
  for (int i = 0; i < 8; ++i) {
    int d0 = (2 * i & 3) + 8 * ((2 * i) >> 2) + 4 * hi;
    uint wA = pkbf(Oa[2 * i] * inv, Oa[2 * i + 1] * inv);
    *(uint*)(Tc + (ln * 128 + ((d0 * 2) ^ ((ln & 7) << 4)))) = wA;
    uint wB = pkbf(Ob[2 * i] * inv, Ob[2 * i + 1] * inv);
    *(uint*)(Tc + (ln * 128 + (((d0 + 32) * 2) ^ ((ln & 7) << 4)))) = wB;
  }
  __threadfence_block();
  u16* Ap = Aout + (size_t)b * TSEQ * DM + h * 64 + (size_t)(q0 + ln) * DM;
#pragma unroll
  for (int j = 0; j < 4; ++j) {
    int oct = hi * 4 + j;
    bf16x8 v = *(const bf16x8*)(Tc + (ln * 128 + ((oct * 16) ^ ((ln & 7) << 4))));
    *(bf16x8*)(Ap + oct * 8) = v;
  }
}

// ---------- output projection: out = attn @ Wo^T + bo (f32 out) ----------
__global__ __launch_bounds__(256) void out_gemm(const u16* __restrict__ attn,
                                                const u16* __restrict__ Wob,
                                                const float* __restrict__ bo,
                                                float* __restrict__ out) {
  __shared__ char lds[32768];
  const int row0 = blockIdx.y * 128, col0 = blockIdx.x * 128;
  f32x4 acc[4][4];
  gemm_tile(attn, Wob, row0, col0, lds, acc);

  const int tid = threadIdx.x;
  const int lane = tid & 63, wid = tid >> 6;
  const int wr = wid >> 1, wc = wid & 1;
  const int lg = lane >> 4, lr = lane & 15;
#pragma unroll
  for (int m = 0; m < 4; ++m)
#pragma unroll
    for (int n = 0; n < 4; ++n) {
      int col = col0 + wc * 64 + n * 16 + lr;
      float b = bo[col];
#pragma unroll
      for (int r = 0; r < 4; ++r) {
        int row = row0 + wr * 64 + m * 16 + lg * 4 + r;
        out[(size_t)row * DM + col] = acc[m][n][r] + b;
      }
    }
}

extern "C" void kernel_launch(void* const* d_in, const int* in_sizes, int n_in,
                              void* d_out, int out_size, void* d_ws, size_t ws_size,
                              hipStream_t stream) {
  const float* x = (const float*)d_in[0];
  const float* Wq = (const float*)d_in[1];
  const float* bq = (const float*)d_in[2];
  const float* Wk = (const float*)d_in[3];
  const float* bk = (const float*)d_in[4];
  const float* Wv = (const float*)d_in[5];
  const float* bv = (const float*)d_in[6];
  const float* Wo = (const float*)d_in[7];
  const float* bo = (const float*)d_in[8];

  char* ws = (char*)d_ws;
  const size_t MB = 1024 * 1024;
  u16* xb = (u16*)(ws);             // 8 MB (x bf16; reused as attn out later)
  u16* Wqb = (u16*)(ws + 8 * MB);   // 2 MB
  u16* Wkb = (u16*)(ws + 10 * MB);  // 2 MB
  u16* Wvb = (u16*)(ws + 12 * MB);  // 2 MB
  u16* Wob = (u16*)(ws + 14 * MB);  // 2 MB
  u16* Qf = (u16*)(ws + 16 * MB);   // 8 MB (fragment-order Q')
  u16* Kf = (u16*)(ws + 24 * MB);   // 8 MB (fragment-order K')
  u16* Vf = (u16*)(ws + 32 * MB);   // 8 MB (fragment-order V')  total 40 MB
  u16* attnb = xb;                  // alias: xb dead after qkv_gemm

  // Wq carries 1/sqrt(Dh) * log2(e); one launch for all conversions
  cvt_all<<<8192, 256, 0, stream>>>(x, Wq, Wk, Wv, Wo, xb, Wqb, Wkb, Wvb, Wob,
                                    0.18033688011112042f);

  qkv_gemm<<<dim3(24, 32), 256, 0, stream>>>(xb, Wqb, Wkb, Wvb, bq, bk, bv, Qf, Kf, Vf);
  attn_kernel<<<dim3(32, 32), 256, 0, stream>>>(Qf, Kf, Vf, attnb);
  out_gemm<<<dim3(8, 32), 256, 0, stream>>>(attnb, Wob, bo, (float*)d_out);
}